// Round 1
// baseline (317.242 us; speedup 1.0000x reference)
//
#include <hip/hip_runtime.h>
#include <cstdint>
#include <cstddef>

__device__ __forceinline__ float lrelu(float v){ return v > 0.f ? v : 0.2f*v; }

// ---------------- CSR build (bucket edges by dst) ----------------
__global__ void k_count(const int* __restrict__ ei, int E, int N, int* __restrict__ deg){
  int i = blockIdx.x*blockDim.x + threadIdx.x;
  int tot = E + N;
  if (i >= tot) return;
  int d = (i < E) ? ei[E + i] : (i - E);
  atomicAdd(&deg[d], 1);
}

// single-block exclusive scan over deg[0..n) -> off[0..n], cur = copy of off
__global__ void k_scan(const int* __restrict__ deg, int* __restrict__ off,
                       int* __restrict__ cur, int n){
  __shared__ int wsum[16];
  __shared__ int wpre[17];
  int tid = threadIdx.x;                 // 1024 threads
  int per = (n + 1023) >> 10;
  int base = tid * per;
  int s = 0;
  for (int i = 0; i < per; i++){ int idx = base + i; if (idx < n) s += deg[idx]; }
  int lane = tid & 63, wv = tid >> 6;
  int v = s;
  for (int d = 1; d < 64; d <<= 1){ int o = __shfl_up(v, d, 64); if (lane >= d) v += o; }
  if (lane == 63) wsum[wv] = v;
  __syncthreads();
  if (tid == 0){ int a = 0; for (int w = 0; w < 16; w++){ wpre[w] = a; a += wsum[w]; } wpre[16] = a; }
  __syncthreads();
  int run = wpre[wv] + (v - s);          // exclusive prefix for this thread
  for (int i = 0; i < per; i++){
    int idx = base + i;
    if (idx < n){ off[idx] = run; cur[idx] = run; run += deg[idx]; }
  }
  if (tid == 0) off[n] = wpre[16];
}

__global__ void k_scatter(const int* __restrict__ ei, int E, int N,
                          int* __restrict__ cur, int* __restrict__ ssrc, int* __restrict__ sdst){
  int i = blockIdx.x*blockDim.x + threadIdx.x;
  int tot = E + N;
  if (i >= tot) return;
  int s = (i < E) ? ei[i]     : (i - E);
  int d = (i < E) ? ei[E + i] : (i - E);
  int pos = atomicAdd(&cur[d], 1);
  ssrc[pos] = s; sdst[pos] = d;
}

// ---------------- conv1 linear: xl1/xr1 = x @ W + b  [N,128] ----------------
__global__ void k_linear1(const float* __restrict__ x,
                          const float* __restrict__ W1l, const float* __restrict__ b1l,
                          const float* __restrict__ W1r, const float* __restrict__ b1r,
                          float* __restrict__ xl1, float* __restrict__ xr1){
  __shared__ float xs[32];
  int n = blockIdx.x, t = threadIdx.x;   // 128 threads
  if (t < 32) xs[t] = x[n*32 + t];
  __syncthreads();
  float al = b1l[t], ar = b1r[t];
  #pragma unroll
  for (int k = 0; k < 32; k++){
    float xv = xs[k];
    al += xv * W1l[k*128 + t];
    ar += xv * W1r[k*128 + t];
  }
  xl1[n*128 + t] = al;
  xr1[n*128 + t] = ar;
}

// ---------------- conv1 edge logits: e[j,h] ----------------
__global__ void k_logits1(const int* __restrict__ ssrc, const int* __restrict__ sdst,
                          const float* __restrict__ xl1, const float* __restrict__ xr1,
                          const float* __restrict__ att1, float* __restrict__ ew, int Etot){
  int t = blockIdx.x*blockDim.x + threadIdx.x;
  int j = t >> 3, h = t & 7;
  if (j >= Etot) return;
  int s = ssrc[j], d = sdst[j];
  const float4* pl = (const float4*)(xl1 + s*128 + h*16);
  const float4* pr = (const float4*)(xr1 + d*128 + h*16);
  const float4* pa = (const float4*)(att1 + h*16);
  float e = 0.f;
  #pragma unroll
  for (int q = 0; q < 4; q++){
    float4 a = pl[q], b = pr[q], wv = pa[q];
    e += lrelu(a.x+b.x)*wv.x + lrelu(a.y+b.y)*wv.y + lrelu(a.z+b.z)*wv.z + lrelu(a.w+b.w)*wv.w;
  }
  ew[j*8 + h] = e;
}

// ---------------- conv1 per-dst softmax over incoming edges (in place) -----
__global__ void k_softmax1(const int* __restrict__ off, float* __restrict__ ew, int N){
  int t = blockIdx.x*blockDim.x + threadIdx.x;
  if (t >= N*8) return;
  int d = t >> 3, h = t & 7;
  int j0 = off[d], j1 = off[d+1];
  float m = -1e30f;
  for (int j = j0; j < j1; j++) m = fmaxf(m, ew[j*8 + h]);
  float s = 0.f;
  for (int j = j0; j < j1; j++) s += __expf(ew[j*8 + h] - m);
  float inv = 1.f / (s + 1e-16f);
  for (int j = j0; j < j1; j++) ew[j*8 + h] = __expf(ew[j*8 + h] - m) * inv;
}

// ---------------- conv1 aggregation: h1[d,f] = sum alpha * xl1[src,f] + bias1
__global__ void k_agg1(const int* __restrict__ off, const int* __restrict__ ssrc,
                       const float* __restrict__ ew, const float* __restrict__ xl1,
                       const float* __restrict__ bias1, float* __restrict__ h1){
  int d = blockIdx.x, f = threadIdx.x;   // 128 threads
  int j0 = off[d], j1 = off[d+1];
  int h = f >> 4;
  float acc = 0.f;
  for (int j = j0; j < j1; j++){
    float a = ew[j*8 + h];
    acc += a * xl1[ssrc[j]*128 + f];
  }
  h1[d*128 + f] = acc + bias1[f];
}

// ---------------- conv2 linear: xl2/xr2 = h1 @ W2 + b2  [N,32] -------------
__global__ void k_linear2(const float* __restrict__ h1,
                          const float* __restrict__ W2l, const float* __restrict__ b2l,
                          const float* __restrict__ W2r, const float* __restrict__ b2r,
                          float* __restrict__ xl2, float* __restrict__ xr2){
  __shared__ float hs[128];
  int n = blockIdx.x, t = threadIdx.x;   // 128 threads
  hs[t] = h1[n*128 + t];
  __syncthreads();
  if (t < 64){
    int c = t & 31;
    bool left = t < 32;
    const float* W = left ? W2l : W2r;
    float a = left ? b2l[c] : b2r[c];
    #pragma unroll 8
    for (int k = 0; k < 128; k++) a += hs[k] * W[k*32 + c];
    if (left) xl2[n*32 + c] = a; else xr2[n*32 + c] = a;
  }
}

// ---------------- conv2 edge logits ----------------
__global__ void k_logits2(const int* __restrict__ ssrc, const int* __restrict__ sdst,
                          const float* __restrict__ xl2, const float* __restrict__ xr2,
                          const float* __restrict__ att2, float* __restrict__ ew2, int Etot){
  int j = blockIdx.x*blockDim.x + threadIdx.x;
  if (j >= Etot) return;
  int s = ssrc[j], d = sdst[j];
  const float4* pl = (const float4*)(xl2 + s*32);
  const float4* pr = (const float4*)(xr2 + d*32);
  const float4* pa = (const float4*)att2;
  float e = 0.f;
  #pragma unroll
  for (int q = 0; q < 8; q++){
    float4 a = pl[q], b = pr[q], wv = pa[q];
    e += lrelu(a.x+b.x)*wv.x + lrelu(a.y+b.y)*wv.y + lrelu(a.z+b.z)*wv.z + lrelu(a.w+b.w)*wv.w;
  }
  ew2[j] = e;
}

__global__ void k_softmax2(const int* __restrict__ off, float* __restrict__ ew2, int N){
  int d = blockIdx.x*blockDim.x + threadIdx.x;
  if (d >= N) return;
  int j0 = off[d], j1 = off[d+1];
  float m = -1e30f;
  for (int j = j0; j < j1; j++) m = fmaxf(m, ew2[j]);
  float s = 0.f;
  for (int j = j0; j < j1; j++) s += __expf(ew2[j] - m);
  float inv = 1.f / (s + 1e-16f);
  for (int j = j0; j < j1; j++) ew2[j] = __expf(ew2[j] - m) * inv;
}

__global__ void k_agg2(const int* __restrict__ off, const int* __restrict__ ssrc,
                       const float* __restrict__ ew2, const float* __restrict__ xl2,
                       const float* __restrict__ bias2, float* __restrict__ h2){
  int t = threadIdx.x;                   // 64 threads, 2 dst per block
  int d = blockIdx.x*2 + (t >> 5);
  int c = t & 31;
  int j0 = off[d], j1 = off[d+1];
  float acc = 0.f;
  for (int j = j0; j < j1; j++) acc += ew2[j] * xl2[ssrc[j]*32 + c];
  h2[d*32 + c] = acc + bias2[c];
}

// ---------------- row L2-normalize: z ----------------
__global__ void k_norm(const float* __restrict__ h2, float* __restrict__ z, int N){
  int t = threadIdx.x;                   // 256 threads = 8 rows
  int row = blockIdx.x*8 + (t >> 5);
  int c = t & 31;
  float v = h2[row*32 + c];
  float ss = v*v;
  #pragma unroll
  for (int d = 16; d > 0; d >>= 1) ss += __shfl_xor(ss, d, 32);
  float nrm = sqrtf(ss);
  z[row*32 + c] = v / fmaxf(nrm, 1e-12f);
}

// ---------------- A_pred = sigmoid(z z^T), 64x64 tile per block ------------
__global__ __launch_bounds__(256) void k_adj(const float* __restrict__ z,
                                             float* __restrict__ out, int N){
  __shared__ float zr[64][33];
  __shared__ float zc[64][33];
  int r0 = blockIdx.y*64, c0 = blockIdx.x*64;
  int tid = threadIdx.x;                 // 256
  for (int i = tid; i < 64*32; i += 256){
    int r = i >> 5, c = i & 31;
    zr[r][c] = z[(size_t)(r0+r)*32 + c];
    zc[r][c] = z[(size_t)(c0+r)*32 + c];
  }
  __syncthreads();
  int tx = tid & 15, ty = tid >> 4;
  float acc[4][4] = {};
  #pragma unroll
  for (int k = 0; k < 32; k++){
    float a0 = zr[ty*4+0][k], a1 = zr[ty*4+1][k], a2 = zr[ty*4+2][k], a3 = zr[ty*4+3][k];
    float b0 = zc[tx*4+0][k], b1 = zc[tx*4+1][k], b2 = zc[tx*4+2][k], b3 = zc[tx*4+3][k];
    acc[0][0] += a0*b0; acc[0][1] += a0*b1; acc[0][2] += a0*b2; acc[0][3] += a0*b3;
    acc[1][0] += a1*b0; acc[1][1] += a1*b1; acc[1][2] += a1*b2; acc[1][3] += a1*b3;
    acc[2][0] += a2*b0; acc[2][1] += a2*b1; acc[2][2] += a2*b2; acc[2][3] += a2*b3;
    acc[3][0] += a3*b0; acc[3][1] += a3*b1; acc[3][2] += a3*b2; acc[3][3] += a3*b3;
  }
  #pragma unroll
  for (int i = 0; i < 4; i++){
    float4 o;
    o.x = 1.f/(1.f + __expf(-acc[i][0]));
    o.y = 1.f/(1.f + __expf(-acc[i][1]));
    o.z = 1.f/(1.f + __expf(-acc[i][2]));
    o.w = 1.f/(1.f + __expf(-acc[i][3]));
    *(float4*)&out[(size_t)(r0 + ty*4 + i)*N + c0 + tx*4] = o;
  }
}

extern "C" void kernel_launch(void* const* d_in, const int* in_sizes, int n_in,
                              void* d_out, int out_size, void* d_ws, size_t ws_size,
                              hipStream_t stream){
  const float* x     = (const float*)d_in[0];
  const int*   ei    = (const int*)  d_in[1];
  const float* W1l   = (const float*)d_in[2];
  const float* b1l   = (const float*)d_in[3];
  const float* W1r   = (const float*)d_in[4];
  const float* b1r   = (const float*)d_in[5];
  const float* att1  = (const float*)d_in[6];
  const float* bias1 = (const float*)d_in[7];
  const float* W2l   = (const float*)d_in[8];
  const float* b2l   = (const float*)d_in[9];
  const float* W2r   = (const float*)d_in[10];
  const float* b2r   = (const float*)d_in[11];
  const float* att2  = (const float*)d_in[12];
  const float* bias2 = (const float*)d_in[13];

  const int N = in_sizes[0] / 32;
  const int E = in_sizes[1] / 2;
  const int Etot = E + N;

  char* w = (char*)d_ws;
  size_t p = 0;
  auto take = [&](size_t bytes)->char*{
    char* r = w + p;
    p = (p + bytes + 255) & ~(size_t)255;
    return r;
  };
  int*   deg  = (int*)  take((size_t)N*4);
  int*   off  = (int*)  take((size_t)(N+1)*4);
  int*   cur  = (int*)  take((size_t)N*4);
  int*   ssrc = (int*)  take((size_t)Etot*4);
  int*   sdst = (int*)  take((size_t)Etot*4);
  float* xl1  = (float*)take((size_t)N*128*4);
  float* xr1  = (float*)take((size_t)N*128*4);
  float* ew   = (float*)take((size_t)Etot*8*4);
  float* h1   = (float*)take((size_t)N*128*4);
  float* xl2  = (float*)take((size_t)N*32*4);
  float* xr2  = (float*)take((size_t)N*32*4);
  float* ew2  = (float*)take((size_t)Etot*4);
  float* h2   = (float*)take((size_t)N*32*4);

  float* Apred = (float*)d_out;
  float* z     = Apred + (size_t)N*N;

  hipMemsetAsync(deg, 0, (size_t)N*4, stream);
  k_count  <<<(Etot+255)/256, 256, 0, stream>>>(ei, E, N, deg);
  k_scan   <<<1, 1024, 0, stream>>>(deg, off, cur, N);
  k_scatter<<<(Etot+255)/256, 256, 0, stream>>>(ei, E, N, cur, ssrc, sdst);

  k_linear1<<<N, 128, 0, stream>>>(x, W1l, b1l, W1r, b1r, xl1, xr1);
  k_logits1<<<(Etot*8+255)/256, 256, 0, stream>>>(ssrc, sdst, xl1, xr1, att1, ew, Etot);
  k_softmax1<<<(N*8+255)/256, 256, 0, stream>>>(off, ew, N);
  k_agg1   <<<N, 128, 0, stream>>>(off, ssrc, ew, xl1, bias1, h1);

  k_linear2<<<N, 128, 0, stream>>>(h1, W2l, b2l, W2r, b2r, xl2, xr2);
  k_logits2<<<(Etot+255)/256, 256, 0, stream>>>(ssrc, sdst, xl2, xr2, att2, ew2, Etot);
  k_softmax2<<<(N+255)/256, 256, 0, stream>>>(off, ew2, N);
  k_agg2   <<<N/2, 64, 0, stream>>>(off, ssrc, ew2, xl2, bias2, h2);

  k_norm   <<<N/8, 256, 0, stream>>>(h2, z, N);

  dim3 grid(N/64, N/64);
  k_adj    <<<grid, 256, 0, stream>>>(z, Apred, N);
}

// Round 3
// 245.005 us; speedup vs baseline: 1.2948x; 1.2948x over previous
//
#include <hip/hip_runtime.h>
#include <cstdint>
#include <cstddef>

typedef float f32x4 __attribute__((ext_vector_type(4)));

__device__ __forceinline__ float lrelu(float v){ return v > 0.f ? v : 0.2f*v; }

// ---------------- CSR build (bucket edges by dst) ----------------
__global__ void k_count(const int* __restrict__ ei, int E, int N, int* __restrict__ deg){
  int i = blockIdx.x*blockDim.x + threadIdx.x;
  int tot = E + N;
  if (i >= tot) return;
  int d = (i < E) ? ei[E + i] : (i - E);
  atomicAdd(&deg[d], 1);
}

// single-block exclusive scan over deg[0..n) -> off[0..n], cur = copy of off
__global__ void k_scan(const int* __restrict__ deg, int* __restrict__ off,
                       int* __restrict__ cur, int n){
  __shared__ int wsum[16];
  __shared__ int wpre[17];
  int tid = threadIdx.x;                 // 1024 threads
  int per = (n + 1023) >> 10;
  int base = tid * per;
  int s = 0;
  for (int i = 0; i < per; i++){ int idx = base + i; if (idx < n) s += deg[idx]; }
  int lane = tid & 63, wv = tid >> 6;
  int v = s;
  for (int d = 1; d < 64; d <<= 1){ int o = __shfl_up(v, d, 64); if (lane >= d) v += o; }
  if (lane == 63) wsum[wv] = v;
  __syncthreads();
  if (tid == 0){ int a = 0; for (int w = 0; w < 16; w++){ wpre[w] = a; a += wsum[w]; } wpre[16] = a; }
  __syncthreads();
  int run = wpre[wv] + (v - s);          // exclusive prefix for this thread
  for (int i = 0; i < per; i++){
    int idx = base + i;
    if (idx < n){ off[idx] = run; cur[idx] = run; run += deg[idx]; }
  }
  if (tid == 0) off[n] = wpre[16];
}

__global__ void k_scatter(const int* __restrict__ ei, int E, int N,
                          int* __restrict__ cur, int* __restrict__ ssrc, int* __restrict__ sdst){
  int i = blockIdx.x*blockDim.x + threadIdx.x;
  int tot = E + N;
  if (i >= tot) return;
  int s = (i < E) ? ei[i]     : (i - E);
  int d = (i < E) ? ei[E + i] : (i - E);
  int pos = atomicAdd(&cur[d], 1);
  ssrc[pos] = s; sdst[pos] = d;
}

// ---------------- conv1 linear: xl1/xr1 = x @ W + b  [N,128] ----------------
__global__ void k_linear1(const float* __restrict__ x,
                          const float* __restrict__ W1l, const float* __restrict__ b1l,
                          const float* __restrict__ W1r, const float* __restrict__ b1r,
                          float* __restrict__ xl1, float* __restrict__ xr1){
  __shared__ float xs[32];
  int n = blockIdx.x, t = threadIdx.x;   // 128 threads
  if (t < 32) xs[t] = x[n*32 + t];
  __syncthreads();
  float al = b1l[t], ar = b1r[t];
  #pragma unroll
  for (int k = 0; k < 32; k++){
    float xv = xs[k];
    al += xv * W1l[k*128 + t];
    ar += xv * W1r[k*128 + t];
  }
  xl1[n*128 + t] = al;
  xr1[n*128 + t] = ar;
}

// ---------------- conv1 edge logits: ew[h][j] (head-major) ----------------
__global__ void k_logits1(const int* __restrict__ ssrc, const int* __restrict__ sdst,
                          const float* __restrict__ xl1, const float* __restrict__ xr1,
                          const float* __restrict__ att1, float* __restrict__ ew, int Etot){
  int j = blockIdx.x*blockDim.x + threadIdx.x;
  int h = blockIdx.y;
  if (j >= Etot) return;
  int s = ssrc[j], d = sdst[j];
  const float4* pl = (const float4*)(xl1 + s*128 + h*16);
  const float4* pr = (const float4*)(xr1 + d*128 + h*16);
  const float4* pa = (const float4*)(att1 + h*16);
  float e = 0.f;
  #pragma unroll
  for (int q = 0; q < 4; q++){
    float4 a = pl[q], b = pr[q], wv = pa[q];
    e += lrelu(a.x+b.x)*wv.x + lrelu(a.y+b.y)*wv.y + lrelu(a.z+b.z)*wv.z + lrelu(a.w+b.w)*wv.w;
  }
  ew[(size_t)h*Etot + j] = e;
}

// ------------ conv1 fused softmax+agg: one block (128 thr) per dst ---------
__global__ __launch_bounds__(128) void k_sa1(const int* __restrict__ off,
                       const int* __restrict__ ssrc, const float* __restrict__ ew,
                       const float* __restrict__ xl1, const float* __restrict__ bias1,
                       float* __restrict__ h1, int Etot){
  int d = blockIdx.x;
  int f = threadIdx.x;                   // 0..127: feature
  int h = f >> 4, q = f & 15;
  const float* ewh = ew + (size_t)h*Etot;
  int j0 = off[d], j1 = off[d+1];
  float m = -1e30f;
  for (int j = j0 + q; j < j1; j += 16) m = fmaxf(m, ewh[j]);
  #pragma unroll
  for (int k = 1; k < 16; k <<= 1) m = fmaxf(m, __shfl_xor(m, k, 64));
  float s = 0.f;
  for (int j = j0 + q; j < j1; j += 16) s += __expf(ewh[j] - m);
  #pragma unroll
  for (int k = 1; k < 16; k <<= 1) s += __shfl_xor(s, k, 64);
  float inv = 1.f / (s + 1e-16f);
  float acc = 0.f;
  for (int j = j0; j < j1; j++){
    float a = __expf(ewh[j] - m) * inv;
    acc += a * xl1[ssrc[j]*128 + f];
  }
  h1[d*128 + f] = acc + bias1[f];
}

// ---------------- conv2 linear: xl2/xr2 = h1 @ W2 + b2  [N,32] -------------
__global__ __launch_bounds__(64) void k_linear2(const float* __restrict__ h1,
                          const float* __restrict__ W2l, const float* __restrict__ b2l,
                          const float* __restrict__ W2r, const float* __restrict__ b2r,
                          float* __restrict__ xl2, float* __restrict__ xr2){
  __shared__ float hs[128];
  int n = blockIdx.x, t = threadIdx.x;   // 64 threads
  hs[t]      = h1[n*128 + t];
  hs[t + 64] = h1[n*128 + t + 64];
  __syncthreads();
  int c = t & 31;
  bool left = t < 32;
  const float* W = left ? W2l : W2r;
  float a = left ? b2l[c] : b2r[c];
  #pragma unroll 8
  for (int k = 0; k < 128; k++) a += hs[k] * W[k*32 + c];
  if (left) xl2[n*32 + c] = a; else xr2[n*32 + c] = a;
}

// ---------------- conv2 edge logits ----------------
__global__ void k_logits2(const int* __restrict__ ssrc, const int* __restrict__ sdst,
                          const float* __restrict__ xl2, const float* __restrict__ xr2,
                          const float* __restrict__ att2, float* __restrict__ ew2, int Etot){
  int j = blockIdx.x*blockDim.x + threadIdx.x;
  if (j >= Etot) return;
  int s = ssrc[j], d = sdst[j];
  const float4* pl = (const float4*)(xl2 + s*32);
  const float4* pr = (const float4*)(xr2 + d*32);
  const float4* pa = (const float4*)att2;
  float e = 0.f;
  #pragma unroll
  for (int q = 0; q < 8; q++){
    float4 a = pl[q], b = pr[q], wv = pa[q];
    e += lrelu(a.x+b.x)*wv.x + lrelu(a.y+b.y)*wv.y + lrelu(a.z+b.z)*wv.z + lrelu(a.w+b.w)*wv.w;
  }
  ew2[j] = e;
}

// ------ conv2 fused softmax+agg+L2norm: wave per dst, 4 dst per block ------
__global__ __launch_bounds__(256) void k_sa2(const int* __restrict__ off,
                       const int* __restrict__ ssrc, const float* __restrict__ ew2,
                       const float* __restrict__ xl2, const float* __restrict__ bias2,
                       float* __restrict__ z){
  int t = threadIdx.x;
  int lane = t & 63;
  int d = blockIdx.x*4 + (t >> 6);
  int j0 = off[d], j1 = off[d+1];
  float m = -1e30f;
  for (int j = j0 + lane; j < j1; j += 64) m = fmaxf(m, ew2[j]);
  #pragma unroll
  for (int k = 1; k < 64; k <<= 1) m = fmaxf(m, __shfl_xor(m, k, 64));
  float s = 0.f;
  for (int j = j0 + lane; j < j1; j += 64) s += __expf(ew2[j] - m);
  #pragma unroll
  for (int k = 1; k < 64; k <<= 1) s += __shfl_xor(s, k, 64);
  float inv = 1.f / (s + 1e-16f);
  int c = lane & 31;
  float acc = 0.f;
  for (int j = j0 + (lane >> 5); j < j1; j += 2)
    acc += __expf(ew2[j] - m) * inv * xl2[ssrc[j]*32 + c];
  acc += __shfl_xor(acc, 32, 64);
  float v = acc + bias2[c];
  float ss = v*v;
  #pragma unroll
  for (int k = 1; k < 32; k <<= 1) ss += __shfl_xor(ss, k, 64);
  if (lane < 32) z[d*32 + c] = v / fmaxf(sqrtf(ss), 1e-12f);
}

// ---------------- A_pred = sigmoid(z z^T), 64x64 tile per block ------------
// LDS tiles stored k-major ([32][68] padded) so the inner loop is ds_read_b128.
__global__ __launch_bounds__(256) void k_adj(const float* __restrict__ z,
                                             float* __restrict__ out, int N){
  __shared__ float zrT[32][68];
  __shared__ float zcT[32][68];
  int r0 = blockIdx.y*64, c0 = blockIdx.x*64;
  int tid = threadIdx.x;                 // 256
  for (int i = tid; i < 64*32; i += 256){
    int r = i >> 5, c = i & 31;          // coalesced read, transposed store
    zrT[c][r] = z[(size_t)(r0+r)*32 + c];
    zcT[c][r] = z[(size_t)(c0+r)*32 + c];
  }
  __syncthreads();
  int tx = tid & 15, ty = tid >> 4;
  float acc[4][4] = {};
  #pragma unroll
  for (int k = 0; k < 32; k++){
    float4 a = *(const float4*)&zrT[k][ty*4];
    float4 b = *(const float4*)&zcT[k][tx*4];
    acc[0][0] += a.x*b.x; acc[0][1] += a.x*b.y; acc[0][2] += a.x*b.z; acc[0][3] += a.x*b.w;
    acc[1][0] += a.y*b.x; acc[1][1] += a.y*b.y; acc[1][2] += a.y*b.z; acc[1][3] += a.y*b.w;
    acc[2][0] += a.z*b.x; acc[2][1] += a.z*b.y; acc[2][2] += a.z*b.z; acc[2][3] += a.z*b.w;
    acc[3][0] += a.w*b.x; acc[3][1] += a.w*b.y; acc[3][2] += a.w*b.z; acc[3][3] += a.w*b.w;
  }
  #pragma unroll
  for (int i = 0; i < 4; i++){
    f32x4 o;
    o.x = 1.f/(1.f + __expf(-acc[i][0]));
    o.y = 1.f/(1.f + __expf(-acc[i][1]));
    o.z = 1.f/(1.f + __expf(-acc[i][2]));
    o.w = 1.f/(1.f + __expf(-acc[i][3]));
    __builtin_nontemporal_store(o, (f32x4*)&out[(size_t)(r0 + ty*4 + i)*N + c0 + tx*4]);
  }
}

extern "C" void kernel_launch(void* const* d_in, const int* in_sizes, int n_in,
                              void* d_out, int out_size, void* d_ws, size_t ws_size,
                              hipStream_t stream){
  const float* x     = (const float*)d_in[0];
  const int*   ei    = (const int*)  d_in[1];
  const float* W1l   = (const float*)d_in[2];
  const float* b1l   = (const float*)d_in[3];
  const float* W1r   = (const float*)d_in[4];
  const float* b1r   = (const float*)d_in[5];
  const float* att1  = (const float*)d_in[6];
  const float* bias1 = (const float*)d_in[7];
  const float* W2l   = (const float*)d_in[8];
  const float* b2l   = (const float*)d_in[9];
  const float* W2r   = (const float*)d_in[10];
  const float* b2r   = (const float*)d_in[11];
  const float* att2  = (const float*)d_in[12];
  const float* bias2 = (const float*)d_in[13];

  const int N = in_sizes[0] / 32;
  const int E = in_sizes[1] / 2;
  const int Etot = E + N;

  char* w = (char*)d_ws;
  size_t p = 0;
  auto take = [&](size_t bytes)->char*{
    char* r = w + p;
    p = (p + bytes + 255) & ~(size_t)255;
    return r;
  };
  int*   deg  = (int*)  take((size_t)N*4);
  int*   off  = (int*)  take((size_t)(N+1)*4);
  int*   cur  = (int*)  take((size_t)N*4);
  int*   ssrc = (int*)  take((size_t)Etot*4);
  int*   sdst = (int*)  take((size_t)Etot*4);
  float* xl1  = (float*)take((size_t)N*128*4);
  float* xr1  = (float*)take((size_t)N*128*4);
  float* ew   = (float*)take((size_t)Etot*8*4);
  float* h1   = (float*)take((size_t)N*128*4);
  float* xl2  = (float*)take((size_t)N*32*4);
  float* xr2  = (float*)take((size_t)N*32*4);
  float* ew2  = (float*)take((size_t)Etot*4);

  float* Apred = (float*)d_out;
  float* z     = Apred + (size_t)N*N;

  (void)hipMemsetAsync(deg, 0, (size_t)N*4, stream);
  k_count  <<<(Etot+255)/256, 256, 0, stream>>>(ei, E, N, deg);
  k_scan   <<<1, 1024, 0, stream>>>(deg, off, cur, N);
  k_scatter<<<(Etot+255)/256, 256, 0, stream>>>(ei, E, N, cur, ssrc, sdst);

  k_linear1<<<N, 128, 0, stream>>>(x, W1l, b1l, W1r, b1r, xl1, xr1);
  dim3 lg1((Etot+255)/256, 8);
  k_logits1<<<lg1, 256, 0, stream>>>(ssrc, sdst, xl1, xr1, att1, ew, Etot);
  k_sa1    <<<N, 128, 0, stream>>>(off, ssrc, ew, xl1, bias1, h1, Etot);

  k_linear2<<<N, 64, 0, stream>>>(h1, W2l, b2l, W2r, b2r, xl2, xr2);
  k_logits2<<<(Etot+255)/256, 256, 0, stream>>>(ssrc, sdst, xl2, xr2, att2, ew2, Etot);
  k_sa2    <<<N/4, 256, 0, stream>>>(off, ssrc, ew2, xl2, bias2, z);

  dim3 grid(N/64, N/64);
  k_adj    <<<grid, 256, 0, stream>>>(z, Apred, N);
}

// Round 4
// 236.502 us; speedup vs baseline: 1.3414x; 1.0360x over previous
//
#include <hip/hip_runtime.h>
#include <hip/hip_bf16.h>
#include <cstdint>
#include <cstddef>

typedef float f32x4 __attribute__((ext_vector_type(4)));
typedef short short8 __attribute__((ext_vector_type(8)));

__device__ __forceinline__ float lrelu(float v){ return v > 0.f ? v : 0.2f*v; }

// ---------------- CSR build (bucket edges by dst) ----------------
__global__ void k_count(const int* __restrict__ ei, int E, int N, int* __restrict__ deg){
  int i = blockIdx.x*blockDim.x + threadIdx.x;
  int tot = E + N;
  if (i >= tot) return;
  int d = (i < E) ? ei[E + i] : (i - E);
  atomicAdd(&deg[d], 1);
}

// single-block exclusive scan over deg[0..n) -> off[0..n], cur = copy of off
__global__ void k_scan(const int* __restrict__ deg, int* __restrict__ off,
                       int* __restrict__ cur, int n){
  __shared__ int wsum[16];
  __shared__ int wpre[17];
  int tid = threadIdx.x;                 // 1024 threads
  int per = (n + 1023) >> 10;
  int base = tid * per;
  int s = 0;
  for (int i = 0; i < per; i++){ int idx = base + i; if (idx < n) s += deg[idx]; }
  int lane = tid & 63, wv = tid >> 6;
  int v = s;
  for (int d = 1; d < 64; d <<= 1){ int o = __shfl_up(v, d, 64); if (lane >= d) v += o; }
  if (lane == 63) wsum[wv] = v;
  __syncthreads();
  if (tid == 0){ int a = 0; for (int w = 0; w < 16; w++){ wpre[w] = a; a += wsum[w]; } wpre[16] = a; }
  __syncthreads();
  int run = wpre[wv] + (v - s);          // exclusive prefix for this thread
  for (int i = 0; i < per; i++){
    int idx = base + i;
    if (idx < n){ off[idx] = run; cur[idx] = run; run += deg[idx]; }
  }
  if (tid == 0) off[n] = wpre[16];
}

__global__ void k_scatter(const int* __restrict__ ei, int E, int N,
                          int* __restrict__ cur, int* __restrict__ ssrc, int* __restrict__ sdst){
  int i = blockIdx.x*blockDim.x + threadIdx.x;
  int tot = E + N;
  if (i >= tot) return;
  int s = (i < E) ? ei[i]     : (i - E);
  int d = (i < E) ? ei[E + i] : (i - E);
  int pos = atomicAdd(&cur[d], 1);
  ssrc[pos] = s; sdst[pos] = d;
}

// ---------------- conv1 linear: xl1/xr1 = x @ W + b  [N,128] ----------------
__global__ void k_linear1(const float* __restrict__ x,
                          const float* __restrict__ W1l, const float* __restrict__ b1l,
                          const float* __restrict__ W1r, const float* __restrict__ b1r,
                          float* __restrict__ xl1, float* __restrict__ xr1){
  __shared__ float xs[32];
  int n = blockIdx.x, t = threadIdx.x;   // 128 threads
  if (t < 32) xs[t] = x[n*32 + t];
  __syncthreads();
  float al = b1l[t], ar = b1r[t];
  #pragma unroll
  for (int k = 0; k < 32; k++){
    float xv = xs[k];
    al += xv * W1l[k*128 + t];
    ar += xv * W1r[k*128 + t];
  }
  xl1[n*128 + t] = al;
  xr1[n*128 + t] = ar;
}

// ---------------- conv1 edge logits: ew[h][j] (head-major) ----------------
__global__ void k_logits1(const int* __restrict__ ssrc, const int* __restrict__ sdst,
                          const float* __restrict__ xl1, const float* __restrict__ xr1,
                          const float* __restrict__ att1, float* __restrict__ ew, int Etot){
  int j = blockIdx.x*blockDim.x + threadIdx.x;
  int h = blockIdx.y;
  if (j >= Etot) return;
  int s = ssrc[j], d = sdst[j];
  const float4* pl = (const float4*)(xl1 + s*128 + h*16);
  const float4* pr = (const float4*)(xr1 + d*128 + h*16);
  const float4* pa = (const float4*)(att1 + h*16);
  float e = 0.f;
  #pragma unroll
  for (int q = 0; q < 4; q++){
    float4 a = pl[q], b = pr[q], wv = pa[q];
    e += lrelu(a.x+b.x)*wv.x + lrelu(a.y+b.y)*wv.y + lrelu(a.z+b.z)*wv.z + lrelu(a.w+b.w)*wv.w;
  }
  ew[(size_t)h*Etot + j] = e;
}

// ------------ conv1 fused softmax+agg: one block (128 thr) per dst ---------
__global__ __launch_bounds__(128) void k_sa1(const int* __restrict__ off,
                       const int* __restrict__ ssrc, const float* __restrict__ ew,
                       const float* __restrict__ xl1, const float* __restrict__ bias1,
                       float* __restrict__ h1, int Etot){
  int d = blockIdx.x;
  int f = threadIdx.x;                   // 0..127: feature
  int h = f >> 4, q = f & 15;
  const float* ewh = ew + (size_t)h*Etot;
  int j0 = off[d], j1 = off[d+1];
  float m = -1e30f;
  for (int j = j0 + q; j < j1; j += 16) m = fmaxf(m, ewh[j]);
  #pragma unroll
  for (int k = 1; k < 16; k <<= 1) m = fmaxf(m, __shfl_xor(m, k, 64));
  float s = 0.f;
  for (int j = j0 + q; j < j1; j += 16) s += __expf(ewh[j] - m);
  #pragma unroll
  for (int k = 1; k < 16; k <<= 1) s += __shfl_xor(s, k, 64);
  float inv = 1.f / (s + 1e-16f);
  float acc = 0.f;
  for (int j = j0; j < j1; j++){
    float a = __expf(ewh[j] - m) * inv;
    acc += a * xl1[ssrc[j]*128 + f];
  }
  h1[d*128 + f] = acc + bias1[f];
}

// ---------------- conv2 linear: xl2/xr2 = h1 @ W2 + b2  [N,32] -------------
__global__ __launch_bounds__(64) void k_linear2(const float* __restrict__ h1,
                          const float* __restrict__ W2l, const float* __restrict__ b2l,
                          const float* __restrict__ W2r, const float* __restrict__ b2r,
                          float* __restrict__ xl2, float* __restrict__ xr2){
  __shared__ float hs[128];
  int n = blockIdx.x, t = threadIdx.x;   // 64 threads
  hs[t]      = h1[n*128 + t];
  hs[t + 64] = h1[n*128 + t + 64];
  __syncthreads();
  int c = t & 31;
  bool left = t < 32;
  const float* W = left ? W2l : W2r;
  float a = left ? b2l[c] : b2r[c];
  #pragma unroll 8
  for (int k = 0; k < 128; k++) a += hs[k] * W[k*32 + c];
  if (left) xl2[n*32 + c] = a; else xr2[n*32 + c] = a;
}

// ---------------- conv2 edge logits ----------------
__global__ void k_logits2(const int* __restrict__ ssrc, const int* __restrict__ sdst,
                          const float* __restrict__ xl2, const float* __restrict__ xr2,
                          const float* __restrict__ att2, float* __restrict__ ew2, int Etot){
  int j = blockIdx.x*blockDim.x + threadIdx.x;
  if (j >= Etot) return;
  int s = ssrc[j], d = sdst[j];
  const float4* pl = (const float4*)(xl2 + s*32);
  const float4* pr = (const float4*)(xr2 + d*32);
  const float4* pa = (const float4*)att2;
  float e = 0.f;
  #pragma unroll
  for (int q = 0; q < 8; q++){
    float4 a = pl[q], b = pr[q], wv = pa[q];
    e += lrelu(a.x+b.x)*wv.x + lrelu(a.y+b.y)*wv.y + lrelu(a.z+b.z)*wv.z + lrelu(a.w+b.w)*wv.w;
  }
  ew2[j] = e;
}

// ------ conv2 fused softmax+agg+L2norm: wave per dst, 4 dst per block ------
// writes z (f32, output) and zb (bf16, for the MFMA zz^T kernel)
__global__ __launch_bounds__(256) void k_sa2(const int* __restrict__ off,
                       const int* __restrict__ ssrc, const float* __restrict__ ew2,
                       const float* __restrict__ xl2, const float* __restrict__ bias2,
                       float* __restrict__ z, __hip_bfloat16* __restrict__ zb){
  int t = threadIdx.x;
  int lane = t & 63;
  int d = blockIdx.x*4 + (t >> 6);
  int j0 = off[d], j1 = off[d+1];
  float m = -1e30f;
  for (int j = j0 + lane; j < j1; j += 64) m = fmaxf(m, ew2[j]);
  #pragma unroll
  for (int k = 1; k < 64; k <<= 1) m = fmaxf(m, __shfl_xor(m, k, 64));
  float s = 0.f;
  for (int j = j0 + lane; j < j1; j += 64) s += __expf(ew2[j] - m);
  #pragma unroll
  for (int k = 1; k < 64; k <<= 1) s += __shfl_xor(s, k, 64);
  float inv = 1.f / (s + 1e-16f);
  int c = lane & 31;
  float acc = 0.f;
  for (int j = j0 + (lane >> 5); j < j1; j += 2)
    acc += __expf(ew2[j] - m) * inv * xl2[ssrc[j]*32 + c];
  acc += __shfl_xor(acc, 32, 64);
  float v = acc + bias2[c];
  float ss = v*v;
  #pragma unroll
  for (int k = 1; k < 32; k <<= 1) ss += __shfl_xor(ss, k, 64);
  if (lane < 32){
    float zv = v / fmaxf(sqrtf(ss), 1e-12f);
    z[d*32 + c] = zv;
    zb[d*32 + c] = __float2bfloat16(zv);
  }
}

// ---------------- A_pred = sigmoid(z z^T) via bf16 MFMA --------------------
// One wave computes a 16x64 strip: 4x mfma_f32_16x16x32_bf16 (K=32 = full dot).
// A and B fragments are loaded identically from zb rows; since both operands
// come from the same matrix with the same (lane,reg)->k mapping, any bijective
// k layout yields dot(z_r, z_c). C/D: col=lane&15, row=(lane>>4)*4+reg (m89).
__global__ __launch_bounds__(256) void k_adj(const __hip_bfloat16* __restrict__ zb,
                                             float* __restrict__ out, int N){
  int tid = threadIdx.x;
  int w = tid >> 6, l = tid & 63;
  int hi = l >> 4, lo = l & 15;
  int r0 = blockIdx.y*64 + w*16;
  int c0 = blockIdx.x*64;
  short8 a = *(const short8*)(zb + (size_t)(r0 + lo)*32 + hi*8);
  f32x4 acc[4];
  #pragma unroll
  for (int ct = 0; ct < 4; ct++){
    short8 b = *(const short8*)(zb + (size_t)(c0 + ct*16 + lo)*32 + hi*8);
    acc[ct] = __builtin_amdgcn_mfma_f32_16x16x32_bf16(a, b, (f32x4){0.f,0.f,0.f,0.f}, 0, 0, 0);
  }
  #pragma unroll
  for (int ct = 0; ct < 4; ct++){
    #pragma unroll
    for (int r = 0; r < 4; r++){
      float v = 1.f/(1.f + __expf(-acc[ct][r]));
      __builtin_nontemporal_store(v, &out[(size_t)(r0 + hi*4 + r)*N + c0 + ct*16 + lo]);
    }
  }
}

extern "C" void kernel_launch(void* const* d_in, const int* in_sizes, int n_in,
                              void* d_out, int out_size, void* d_ws, size_t ws_size,
                              hipStream_t stream){
  const float* x     = (const float*)d_in[0];
  const int*   ei    = (const int*)  d_in[1];
  const float* W1l   = (const float*)d_in[2];
  const float* b1l   = (const float*)d_in[3];
  const float* W1r   = (const float*)d_in[4];
  const float* b1r   = (const float*)d_in[5];
  const float* att1  = (const float*)d_in[6];
  const float* bias1 = (const float*)d_in[7];
  const float* W2l   = (const float*)d_in[8];
  const float* b2l   = (const float*)d_in[9];
  const float* W2r   = (const float*)d_in[10];
  const float* b2r   = (const float*)d_in[11];
  const float* att2  = (const float*)d_in[12];
  const float* bias2 = (const float*)d_in[13];

  const int N = in_sizes[0] / 32;
  const int E = in_sizes[1] / 2;
  const int Etot = E + N;

  char* w = (char*)d_ws;
  size_t p = 0;
  auto take = [&](size_t bytes)->char*{
    char* r = w + p;
    p = (p + bytes + 255) & ~(size_t)255;
    return r;
  };
  int*   deg  = (int*)  take((size_t)N*4);
  int*   off  = (int*)  take((size_t)(N+1)*4);
  int*   cur  = (int*)  take((size_t)N*4);
  int*   ssrc = (int*)  take((size_t)Etot*4);
  int*   sdst = (int*)  take((size_t)Etot*4);
  float* xl1  = (float*)take((size_t)N*128*4);
  float* xr1  = (float*)take((size_t)N*128*4);
  float* ew   = (float*)take((size_t)Etot*8*4);
  float* h1   = (float*)take((size_t)N*128*4);
  float* xl2  = (float*)take((size_t)N*32*4);
  float* xr2  = (float*)take((size_t)N*32*4);
  float* ew2  = (float*)take((size_t)Etot*4);
  __hip_bfloat16* zb = (__hip_bfloat16*)take((size_t)N*32*2);

  float* Apred = (float*)d_out;
  float* z     = Apred + (size_t)N*N;

  (void)hipMemsetAsync(deg, 0, (size_t)N*4, stream);
  k_count  <<<(Etot+255)/256, 256, 0, stream>>>(ei, E, N, deg);
  k_scan   <<<1, 1024, 0, stream>>>(deg, off, cur, N);
  k_scatter<<<(Etot+255)/256, 256, 0, stream>>>(ei, E, N, cur, ssrc, sdst);

  k_linear1<<<N, 128, 0, stream>>>(x, W1l, b1l, W1r, b1r, xl1, xr1);
  dim3 lg1((Etot+255)/256, 8);
  k_logits1<<<lg1, 256, 0, stream>>>(ssrc, sdst, xl1, xr1, att1, ew, Etot);
  k_sa1    <<<N, 128, 0, stream>>>(off, ssrc, ew, xl1, bias1, h1, Etot);

  k_linear2<<<N, 64, 0, stream>>>(h1, W2l, b2l, W2r, b2r, xl2, xr2);
  k_logits2<<<(Etot+255)/256, 256, 0, stream>>>(ssrc, sdst, xl2, xr2, att2, ew2, Etot);
  k_sa2    <<<N/4, 256, 0, stream>>>(off, ssrc, ew2, xl2, bias2, z, zb);

  dim3 grid(N/64, N/64);
  k_adj    <<<grid, 256, 0, stream>>>(zb, Apred, N);
}

// Round 5
// 234.363 us; speedup vs baseline: 1.3536x; 1.0091x over previous
//
#include <hip/hip_runtime.h>
#include <hip/hip_bf16.h>
#include <cstdint>
#include <cstddef>

typedef float f32x4 __attribute__((ext_vector_type(4)));
typedef short short8 __attribute__((ext_vector_type(8)));

__device__ __forceinline__ float lrelu(float v){ return v > 0.f ? v : 0.2f*v; }

// ---------------- CSR build (bucket edges by dst) ----------------
__global__ void k_count(const int* __restrict__ ei, int E, int N, int* __restrict__ deg){
  int i = blockIdx.x*blockDim.x + threadIdx.x;
  int tot = E + N;
  if (i >= tot) return;
  int d = (i < E) ? ei[E + i] : (i - E);
  atomicAdd(&deg[d], 1);
}

// single-block exclusive scan over deg[0..n) -> off[0..n], cur = copy of off
__global__ void k_scan(const int* __restrict__ deg, int* __restrict__ off,
                       int* __restrict__ cur, int n){
  __shared__ int wsum[16];
  __shared__ int wpre[17];
  int tid = threadIdx.x;                 // 1024 threads
  int per = (n + 1023) >> 10;
  int base = tid * per;
  int s = 0;
  for (int i = 0; i < per; i++){ int idx = base + i; if (idx < n) s += deg[idx]; }
  int lane = tid & 63, wv = tid >> 6;
  int v = s;
  for (int d = 1; d < 64; d <<= 1){ int o = __shfl_up(v, d, 64); if (lane >= d) v += o; }
  if (lane == 63) wsum[wv] = v;
  __syncthreads();
  if (tid == 0){ int a = 0; for (int w = 0; w < 16; w++){ wpre[w] = a; a += wsum[w]; } wpre[16] = a; }
  __syncthreads();
  int run = wpre[wv] + (v - s);          // exclusive prefix for this thread
  for (int i = 0; i < per; i++){
    int idx = base + i;
    if (idx < n){ off[idx] = run; cur[idx] = run; run += deg[idx]; }
  }
  if (tid == 0) off[n] = wpre[16];
}

__global__ void k_scatter(const int* __restrict__ ei, int E, int N,
                          int* __restrict__ cur, int* __restrict__ ssrc, int* __restrict__ sdst){
  int i = blockIdx.x*blockDim.x + threadIdx.x;
  int tot = E + N;
  if (i >= tot) return;
  int s = (i < E) ? ei[i]     : (i - E);
  int d = (i < E) ? ei[E + i] : (i - E);
  int pos = atomicAdd(&cur[d], 1);
  ssrc[pos] = s; sdst[pos] = d;
}

// ------- conv1 linear: xl1/xr1 = x @ W + b  [N,128]; W cols in regs -------
__global__ __launch_bounds__(128) void k_linear1(const float* __restrict__ x,
                          const float* __restrict__ W1l, const float* __restrict__ b1l,
                          const float* __restrict__ W1r, const float* __restrict__ b1r,
                          float* __restrict__ xl1, float* __restrict__ xr1){
  __shared__ float xs[16][32];
  int t = threadIdx.x;
  int r0 = blockIdx.x * 16;
  float wl[32], wr[32];
  #pragma unroll
  for (int k = 0; k < 32; k++){ wl[k] = W1l[k*128 + t]; wr[k] = W1r[k*128 + t]; }
  float bl = b1l[t], br = b1r[t];
  #pragma unroll
  for (int i = 0; i < 4; i++){
    int idx = t + i*128;                 // 0..511
    xs[idx >> 5][idx & 31] = x[r0*32 + idx];
  }
  __syncthreads();
  #pragma unroll 4
  for (int r = 0; r < 16; r++){
    float al = bl, ar = br;
    const float4* xv4 = (const float4*)xs[r];
    #pragma unroll
    for (int q = 0; q < 8; q++){
      float4 xv = xv4[q];
      al += xv.x*wl[q*4+0] + xv.y*wl[q*4+1] + xv.z*wl[q*4+2] + xv.w*wl[q*4+3];
      ar += xv.x*wr[q*4+0] + xv.y*wr[q*4+1] + xv.z*wr[q*4+2] + xv.w*wr[q*4+3];
    }
    xl1[(r0+r)*128 + t] = al;
    xr1[(r0+r)*128 + t] = ar;
  }
}

// ------- conv1 fused logits+softmax+agg: one block (128 thr) per dst -------
#define ECAP1 192
__global__ __launch_bounds__(128) void k_conv1(const int* __restrict__ off,
                       const int* __restrict__ ssrc,
                       const float* __restrict__ xl1, const float* __restrict__ xr1,
                       const float* __restrict__ att1, const float* __restrict__ bias1,
                       float* __restrict__ h1){
  __shared__ float elds[ECAP1*8];        // [jj][h], 6 KB
  int d = blockIdx.x;
  int f = threadIdx.x;                   // feature 0..127
  int h = f >> 4, q = f & 15;
  int j0 = off[d], deg = off[d+1] - j0;
  int dn = min(deg, ECAP1);
  float xr_f = xr1[d*128 + f];
  float at_f = att1[f];                  // att1 is [8][16] row-major = [h][c]
  // phase 1: per-edge logits via 16-lane dot-reduce
  #pragma unroll 2
  for (int jj = 0; jj < dn; jj++){
    int s = ssrc[j0 + jj];
    float tv = lrelu(xl1[s*128 + f] + xr_f) * at_f;
    #pragma unroll
    for (int k = 1; k < 16; k <<= 1) tv += __shfl_xor(tv, k, 64);
    if (q == 0) elds[jj*8 + h] = tv;
  }
  __syncthreads();
  // softmax over incoming edges (per head, q-strided)
  float m = -1e30f;
  for (int jj = q; jj < dn; jj += 16) m = fmaxf(m, elds[jj*8 + h]);
  #pragma unroll
  for (int k = 1; k < 16; k <<= 1) m = fmaxf(m, __shfl_xor(m, k, 64));
  float sm = 0.f;
  for (int jj = q; jj < dn; jj += 16) sm += __expf(elds[jj*8 + h] - m);
  #pragma unroll
  for (int k = 1; k < 16; k <<= 1) sm += __shfl_xor(sm, k, 64);
  float inv = 1.f / (sm + 1e-16f);
  for (int jj = q; jj < dn; jj += 16) elds[jj*8 + h] = __expf(elds[jj*8 + h] - m) * inv;
  __syncthreads();
  // phase 2: aggregate
  float acc = 0.f;
  #pragma unroll 2
  for (int jj = 0; jj < dn; jj++){
    int s = ssrc[j0 + jj];
    acc += elds[jj*8 + h] * xl1[s*128 + f];
  }
  h1[d*128 + f] = acc + bias1[f];
}

// ---------------- conv2 linear: xl2/xr2 = h1 @ W2 + b2  [N,32] -------------
__global__ __launch_bounds__(64) void k_linear2(const float* __restrict__ h1,
                          const float* __restrict__ W2l, const float* __restrict__ b2l,
                          const float* __restrict__ W2r, const float* __restrict__ b2r,
                          float* __restrict__ xl2, float* __restrict__ xr2){
  __shared__ float hs[128];
  int n = blockIdx.x, t = threadIdx.x;   // 64 threads
  hs[t]      = h1[n*128 + t];
  hs[t + 64] = h1[n*128 + t + 64];
  __syncthreads();
  int c = t & 31;
  bool left = t < 32;
  const float* W = left ? W2l : W2r;
  float a = left ? b2l[c] : b2r[c];
  #pragma unroll 8
  for (int k = 0; k < 128; k++) a += hs[k] * W[k*32 + c];
  if (left) xl2[n*32 + c] = a; else xr2[n*32 + c] = a;
}

// -- conv2 fused logits+softmax+agg+L2norm: wave per dst, 4 dst per block --
#define ECAP2 256
__global__ __launch_bounds__(256) void k_conv2(const int* __restrict__ off,
                       const int* __restrict__ ssrc,
                       const float* __restrict__ xl2, const float* __restrict__ xr2,
                       const float* __restrict__ att2, const float* __restrict__ bias2,
                       float* __restrict__ z, __hip_bfloat16* __restrict__ zb){
  __shared__ float elds[4][ECAP2];       // 4 KB
  int t = threadIdx.x;
  int w = t >> 6, lane = t & 63;
  int half = lane >> 5, c = lane & 31;
  int d = blockIdx.x*4 + w;
  int j0 = off[d], deg = off[d+1] - j0;
  int dn = min(deg, ECAP2);
  float xr_c = xr2[d*32 + c];
  float at_c = att2[c];
  // phase 1: logits, two edges per wave (one per 32-lane half)
  for (int jj = half; jj < dn; jj += 2){
    int s = ssrc[j0 + jj];
    float tv = lrelu(xl2[s*32 + c] + xr_c) * at_c;
    #pragma unroll
    for (int k = 1; k < 32; k <<= 1) tv += __shfl_xor(tv, k, 64);
    if (c == 0) elds[w][jj] = tv;
  }
  __syncthreads();
  float m = -1e30f;
  for (int jj = lane; jj < dn; jj += 64) m = fmaxf(m, elds[w][jj]);
  #pragma unroll
  for (int k = 1; k < 64; k <<= 1) m = fmaxf(m, __shfl_xor(m, k, 64));
  float sm = 0.f;
  for (int jj = lane; jj < dn; jj += 64) sm += __expf(elds[w][jj] - m);
  #pragma unroll
  for (int k = 1; k < 64; k <<= 1) sm += __shfl_xor(sm, k, 64);
  float inv = 1.f / (sm + 1e-16f);
  for (int jj = lane; jj < dn; jj += 64) elds[w][jj] = __expf(elds[w][jj] - m) * inv;
  __syncthreads();
  // phase 2: aggregate + bias + L2 normalize
  float acc = 0.f;
  for (int jj = half; jj < dn; jj += 2)
    acc += elds[w][jj] * xl2[ssrc[j0 + jj]*32 + c];
  acc += __shfl_xor(acc, 32, 64);
  float v = acc + bias2[c];
  float ss = v*v;
  #pragma unroll
  for (int k = 1; k < 32; k <<= 1) ss += __shfl_xor(ss, k, 64);
  if (half == 0){
    float zv = v / fmaxf(sqrtf(ss), 1e-12f);
    z[d*32 + c] = zv;
    zb[d*32 + c] = __float2bfloat16(zv);
  }
}

// ---------------- A_pred = sigmoid(z z^T) via bf16 MFMA --------------------
__global__ __launch_bounds__(256) void k_adj(const __hip_bfloat16* __restrict__ zb,
                                             float* __restrict__ out, int N){
  int tid = threadIdx.x;
  int w = tid >> 6, l = tid & 63;
  int hi = l >> 4, lo = l & 15;
  int r0 = blockIdx.y*64 + w*16;
  int c0 = blockIdx.x*64;
  short8 a = *(const short8*)(zb + (size_t)(r0 + lo)*32 + hi*8);
  f32x4 acc[4];
  #pragma unroll
  for (int ct = 0; ct < 4; ct++){
    short8 b = *(const short8*)(zb + (size_t)(c0 + ct*16 + lo)*32 + hi*8);
    acc[ct] = __builtin_amdgcn_mfma_f32_16x16x32_bf16(a, b, (f32x4){0.f,0.f,0.f,0.f}, 0, 0, 0);
  }
  #pragma unroll
  for (int ct = 0; ct < 4; ct++){
    #pragma unroll
    for (int r = 0; r < 4; r++){
      float v = 1.f/(1.f + __expf(-acc[ct][r]));
      __builtin_nontemporal_store(v, &out[(size_t)(r0 + hi*4 + r)*N + c0 + ct*16 + lo]);
    }
  }
}

extern "C" void kernel_launch(void* const* d_in, const int* in_sizes, int n_in,
                              void* d_out, int out_size, void* d_ws, size_t ws_size,
                              hipStream_t stream){
  const float* x     = (const float*)d_in[0];
  const int*   ei    = (const int*)  d_in[1];
  const float* W1l   = (const float*)d_in[2];
  const float* b1l   = (const float*)d_in[3];
  const float* W1r   = (const float*)d_in[4];
  const float* b1r   = (const float*)d_in[5];
  const float* att1  = (const float*)d_in[6];
  const float* bias1 = (const float*)d_in[7];
  const float* W2l   = (const float*)d_in[8];
  const float* b2l   = (const float*)d_in[9];
  const float* W2r   = (const float*)d_in[10];
  const float* b2r   = (const float*)d_in[11];
  const float* att2  = (const float*)d_in[12];
  const float* bias2 = (const float*)d_in[13];

  const int N = in_sizes[0] / 32;
  const int E = in_sizes[1] / 2;
  const int Etot = E + N;

  char* w = (char*)d_ws;
  size_t p = 0;
  auto take = [&](size_t bytes)->char*{
    char* r = w + p;
    p = (p + bytes + 255) & ~(size_t)255;
    return r;
  };
  int*   deg  = (int*)  take((size_t)N*4);
  int*   off  = (int*)  take((size_t)(N+1)*4);
  int*   cur  = (int*)  take((size_t)N*4);
  int*   ssrc = (int*)  take((size_t)Etot*4);
  int*   sdst = (int*)  take((size_t)Etot*4);
  float* xl1  = (float*)take((size_t)N*128*4);
  float* xr1  = (float*)take((size_t)N*128*4);
  float* h1   = (float*)take((size_t)N*128*4);
  float* xl2  = (float*)take((size_t)N*32*4);
  float* xr2  = (float*)take((size_t)N*32*4);
  __hip_bfloat16* zb = (__hip_bfloat16*)take((size_t)N*32*2);

  float* Apred = (float*)d_out;
  float* z     = Apred + (size_t)N*N;

  (void)hipMemsetAsync(deg, 0, (size_t)N*4, stream);
  k_count  <<<(Etot+255)/256, 256, 0, stream>>>(ei, E, N, deg);
  k_scan   <<<1, 1024, 0, stream>>>(deg, off, cur, N);
  k_scatter<<<(Etot+255)/256, 256, 0, stream>>>(ei, E, N, cur, ssrc, sdst);

  k_linear1<<<N/16, 128, 0, stream>>>(x, W1l, b1l, W1r, b1r, xl1, xr1);
  k_conv1  <<<N, 128, 0, stream>>>(off, ssrc, xl1, xr1, att1, bias1, h1);

  k_linear2<<<N, 64, 0, stream>>>(h1, W2l, b2l, W2r, b2r, xl2, xr2);
  k_conv2  <<<N/4, 256, 0, stream>>>(off, ssrc, xl2, xr2, att2, bias2, z, zb);

  dim3 grid(N/64, N/64);
  k_adj    <<<grid, 256, 0, stream>>>(zb, Apred, N);
}

// Round 6
// 199.929 us; speedup vs baseline: 1.5868x; 1.1722x over previous
//
#include <hip/hip_runtime.h>
#include <hip/hip_bf16.h>
#include <cstdint>
#include <cstddef>

typedef float f32x4 __attribute__((ext_vector_type(4)));
typedef short short8 __attribute__((ext_vector_type(8)));

__device__ __forceinline__ float lrelu(float v){ return v > 0.f ? v : 0.2f*v; }

// ---------------- CSR build (bucket edges by dst) ----------------
__global__ void k_count(const int* __restrict__ ei, int E, int N, int* __restrict__ deg){
  int i = blockIdx.x*blockDim.x + threadIdx.x;
  int tot = E + N;
  if (i >= tot) return;
  int d = (i < E) ? ei[E + i] : (i - E);
  atomicAdd(&deg[d], 1);
}

// single-block exclusive scan over deg[0..n) -> off[0..n], cur = copy of off
__global__ void k_scan(const int* __restrict__ deg, int* __restrict__ off,
                       int* __restrict__ cur, int n){
  __shared__ int wsum[16];
  __shared__ int wpre[17];
  int tid = threadIdx.x;                 // 1024 threads
  int per = (n + 1023) >> 10;
  int base = tid * per;
  int s = 0;
  for (int i = 0; i < per; i++){ int idx = base + i; if (idx < n) s += deg[idx]; }
  int lane = tid & 63, wv = tid >> 6;
  int v = s;
  for (int d = 1; d < 64; d <<= 1){ int o = __shfl_up(v, d, 64); if (lane >= d) v += o; }
  if (lane == 63) wsum[wv] = v;
  __syncthreads();
  if (tid == 0){ int a = 0; for (int w = 0; w < 16; w++){ wpre[w] = a; a += wsum[w]; } wpre[16] = a; }
  __syncthreads();
  int run = wpre[wv] + (v - s);          // exclusive prefix for this thread
  for (int i = 0; i < per; i++){
    int idx = base + i;
    if (idx < n){ off[idx] = run; cur[idx] = run; run += deg[idx]; }
  }
  if (tid == 0) off[n] = wpre[16];
}

__global__ void k_scatter(const int* __restrict__ ei, int E, int N,
                          int* __restrict__ cur, int* __restrict__ ssrc, int* __restrict__ sdst){
  int i = blockIdx.x*blockDim.x + threadIdx.x;
  int tot = E + N;
  if (i >= tot) return;
  int s = (i < E) ? ei[i]     : (i - E);
  int d = (i < E) ? ei[E + i] : (i - E);
  int pos = atomicAdd(&cur[d], 1);
  ssrc[pos] = s; sdst[pos] = d;
}

// ------- conv1 linear: xl1/xr1 = x @ W + b  [N,128]; W cols in regs -------
__global__ __launch_bounds__(128) void k_linear1(const float* __restrict__ x,
                          const float* __restrict__ W1l, const float* __restrict__ b1l,
                          const float* __restrict__ W1r, const float* __restrict__ b1r,
                          float* __restrict__ xl1, float* __restrict__ xr1){
  __shared__ float xs[16][32];
  int t = threadIdx.x;
  int r0 = blockIdx.x * 16;
  float wl[32], wr[32];
  #pragma unroll
  for (int k = 0; k < 32; k++){ wl[k] = W1l[k*128 + t]; wr[k] = W1r[k*128 + t]; }
  float bl = b1l[t], br = b1r[t];
  #pragma unroll
  for (int i = 0; i < 4; i++){
    int idx = t + i*128;                 // 0..511
    xs[idx >> 5][idx & 31] = x[r0*32 + idx];
  }
  __syncthreads();
  #pragma unroll 4
  for (int r = 0; r < 16; r++){
    float al = bl, ar = br;
    const float4* xv4 = (const float4*)xs[r];
    #pragma unroll
    for (int q = 0; q < 8; q++){
      float4 xv = xv4[q];
      al += xv.x*wl[q*4+0] + xv.y*wl[q*4+1] + xv.z*wl[q*4+2] + xv.w*wl[q*4+3];
      ar += xv.x*wr[q*4+0] + xv.y*wr[q*4+1] + xv.z*wr[q*4+2] + xv.w*wr[q*4+3];
    }
    xl1[(r0+r)*128 + t] = al;
    xr1[(r0+r)*128 + t] = ar;
  }
}

// ------- conv1 fused logits+softmax+agg: one block (128 thr) per dst -------
#define ECAP1 192
__global__ __launch_bounds__(128) void k_conv1(const int* __restrict__ off,
                       const int* __restrict__ ssrc,
                       const float* __restrict__ xl1, const float* __restrict__ xr1,
                       const float* __restrict__ att1, const float* __restrict__ bias1,
                       float* __restrict__ h1){
  __shared__ float elds[ECAP1*8];        // [jj][h], 6 KB
  int d = blockIdx.x;
  int f = threadIdx.x;                   // feature 0..127
  int h = f >> 4, q = f & 15;
  int j0 = off[d], deg = off[d+1] - j0;
  int dn = min(deg, ECAP1);
  float xr_f = xr1[d*128 + f];
  float at_f = att1[f];                  // att1 is [8][16] row-major = [h][c]
  // phase 1: per-edge logits via 16-lane dot-reduce
  #pragma unroll 2
  for (int jj = 0; jj < dn; jj++){
    int s = ssrc[j0 + jj];
    float tv = lrelu(xl1[s*128 + f] + xr_f) * at_f;
    #pragma unroll
    for (int k = 1; k < 16; k <<= 1) tv += __shfl_xor(tv, k, 64);
    if (q == 0) elds[jj*8 + h] = tv;
  }
  __syncthreads();
  // softmax over incoming edges (per head, q-strided)
  float m = -1e30f;
  for (int jj = q; jj < dn; jj += 16) m = fmaxf(m, elds[jj*8 + h]);
  #pragma unroll
  for (int k = 1; k < 16; k <<= 1) m = fmaxf(m, __shfl_xor(m, k, 64));
  float sm = 0.f;
  for (int jj = q; jj < dn; jj += 16) sm += __expf(elds[jj*8 + h] - m);
  #pragma unroll
  for (int k = 1; k < 16; k <<= 1) sm += __shfl_xor(sm, k, 64);
  float inv = 1.f / (sm + 1e-16f);
  for (int jj = q; jj < dn; jj += 16) elds[jj*8 + h] = __expf(elds[jj*8 + h] - m) * inv;
  __syncthreads();
  // phase 2: aggregate
  float acc = 0.f;
  #pragma unroll 2
  for (int jj = 0; jj < dn; jj++){
    int s = ssrc[j0 + jj];
    acc += elds[jj*8 + h] * xl1[s*128 + f];
  }
  h1[d*128 + f] = acc + bias1[f];
}

// ---------------- conv2 linear: xl2/xr2 = h1 @ W2 + b2  [N,32] -------------
__global__ __launch_bounds__(64) void k_linear2(const float* __restrict__ h1,
                          const float* __restrict__ W2l, const float* __restrict__ b2l,
                          const float* __restrict__ W2r, const float* __restrict__ b2r,
                          float* __restrict__ xl2, float* __restrict__ xr2){
  __shared__ float hs[128];
  int n = blockIdx.x, t = threadIdx.x;   // 64 threads
  hs[t]      = h1[n*128 + t];
  hs[t + 64] = h1[n*128 + t + 64];
  __syncthreads();
  int c = t & 31;
  bool left = t < 32;
  const float* W = left ? W2l : W2r;
  float a = left ? b2l[c] : b2r[c];
  #pragma unroll 8
  for (int k = 0; k < 128; k++) a += hs[k] * W[k*32 + c];
  if (left) xl2[n*32 + c] = a; else xr2[n*32 + c] = a;
}

// -- conv2 fused logits+softmax+agg+L2norm: wave per dst, 4 dst per block --
#define ECAP2 256
__global__ __launch_bounds__(256) void k_conv2(const int* __restrict__ off,
                       const int* __restrict__ ssrc,
                       const float* __restrict__ xl2, const float* __restrict__ xr2,
                       const float* __restrict__ att2, const float* __restrict__ bias2,
                       float* __restrict__ z, __hip_bfloat16* __restrict__ zb){
  __shared__ float elds[4][ECAP2];       // 4 KB
  int t = threadIdx.x;
  int w = t >> 6, lane = t & 63;
  int half = lane >> 5, c = lane & 31;
  int d = blockIdx.x*4 + w;
  int j0 = off[d], deg = off[d+1] - j0;
  int dn = min(deg, ECAP2);
  float xr_c = xr2[d*32 + c];
  float at_c = att2[c];
  // phase 1: logits, two edges per wave (one per 32-lane half)
  for (int jj = half; jj < dn; jj += 2){
    int s = ssrc[j0 + jj];
    float tv = lrelu(xl2[s*32 + c] + xr_c) * at_c;
    #pragma unroll
    for (int k = 1; k < 32; k <<= 1) tv += __shfl_xor(tv, k, 64);
    if (c == 0) elds[w][jj] = tv;
  }
  __syncthreads();
  float m = -1e30f;
  for (int jj = lane; jj < dn; jj += 64) m = fmaxf(m, elds[w][jj]);
  #pragma unroll
  for (int k = 1; k < 64; k <<= 1) m = fmaxf(m, __shfl_xor(m, k, 64));
  float sm = 0.f;
  for (int jj = lane; jj < dn; jj += 64) sm += __expf(elds[w][jj] - m);
  #pragma unroll
  for (int k = 1; k < 64; k <<= 1) sm += __shfl_xor(sm, k, 64);
  float inv = 1.f / (sm + 1e-16f);
  for (int jj = lane; jj < dn; jj += 64) elds[w][jj] = __expf(elds[w][jj] - m) * inv;
  __syncthreads();
  // phase 2: aggregate + bias + L2 normalize
  float acc = 0.f;
  for (int jj = half; jj < dn; jj += 2)
    acc += elds[w][jj] * xl2[ssrc[j0 + jj]*32 + c];
  acc += __shfl_xor(acc, 32, 64);
  float v = acc + bias2[c];
  float ss = v*v;
  #pragma unroll
  for (int k = 1; k < 32; k <<= 1) ss += __shfl_xor(ss, k, 64);
  if (half == 0){
    float zv = v / fmaxf(sqrtf(ss), 1e-12f);
    z[d*32 + c] = zv;
    zb[d*32 + c] = __float2bfloat16(zv);
  }
}

// ---------------- A_pred = sigmoid(z z^T) via bf16 MFMA --------------------
// MFMA math unchanged; epilogue bounces through LDS so global stores are
// float4 with 16 consecutive lanes covering 256 B contiguous per instruction.
__global__ __launch_bounds__(256) void k_adj(const __hip_bfloat16* __restrict__ zb,
                                             float* __restrict__ out, int N){
  __shared__ float tile[64][68];         // pad 68: aligned float4, ~2-way banks
  int tid = threadIdx.x;
  int w = tid >> 6, l = tid & 63;
  int hi = l >> 4, lo = l & 15;
  int r0 = blockIdx.y*64, c0 = blockIdx.x*64;
  short8 a = *(const short8*)(zb + (size_t)(r0 + w*16 + lo)*32 + hi*8);
  f32x4 acc[4];
  #pragma unroll
  for (int ct = 0; ct < 4; ct++){
    short8 b = *(const short8*)(zb + (size_t)(c0 + ct*16 + lo)*32 + hi*8);
    acc[ct] = __builtin_amdgcn_mfma_f32_16x16x32_bf16(a, b, (f32x4){0.f,0.f,0.f,0.f}, 0, 0, 0);
  }
  #pragma unroll
  for (int ct = 0; ct < 4; ct++){
    #pragma unroll
    for (int r = 0; r < 4; r++)
      tile[w*16 + hi*4 + r][ct*16 + lo] = 1.f/(1.f + __expf(-acc[ct][r]));
  }
  __syncthreads();
  #pragma unroll
  for (int k = 0; k < 4; k++){
    int g = tid + k*256;                 // 0..1023 float4 slots
    int row = g >> 4, c4 = (g & 15)*4;
    f32x4 v = *(const f32x4*)&tile[row][c4];
    __builtin_nontemporal_store(v, (f32x4*)&out[(size_t)(r0 + row)*N + c0 + c4]);
  }
}

extern "C" void kernel_launch(void* const* d_in, const int* in_sizes, int n_in,
                              void* d_out, int out_size, void* d_ws, size_t ws_size,
                              hipStream_t stream){
  const float* x     = (const float*)d_in[0];
  const int*   ei    = (const int*)  d_in[1];
  const float* W1l   = (const float*)d_in[2];
  const float* b1l   = (const float*)d_in[3];
  const float* W1r   = (const float*)d_in[4];
  const float* b1r   = (const float*)d_in[5];
  const float* att1  = (const float*)d_in[6];
  const float* bias1 = (const float*)d_in[7];
  const float* W2l   = (const float*)d_in[8];
  const float* b2l   = (const float*)d_in[9];
  const float* W2r   = (const float*)d_in[10];
  const float* b2r   = (const float*)d_in[11];
  const float* att2  = (const float*)d_in[12];
  const float* bias2 = (const float*)d_in[13];

  const int N = in_sizes[0] / 32;
  const int E = in_sizes[1] / 2;
  const int Etot = E + N;

  char* w = (char*)d_ws;
  size_t p = 0;
  auto take = [&](size_t bytes)->char*{
    char* r = w + p;
    p = (p + bytes + 255) & ~(size_t)255;
    return r;
  };
  int*   deg  = (int*)  take((size_t)N*4);
  int*   off  = (int*)  take((size_t)(N+1)*4);
  int*   cur  = (int*)  take((size_t)N*4);
  int*   ssrc = (int*)  take((size_t)Etot*4);
  int*   sdst = (int*)  take((size_t)Etot*4);
  float* xl1  = (float*)take((size_t)N*128*4);
  float* xr1  = (float*)take((size_t)N*128*4);
  float* h1   = (float*)take((size_t)N*128*4);
  float* xl2  = (float*)take((size_t)N*32*4);
  float* xr2  = (float*)take((size_t)N*32*4);
  __hip_bfloat16* zb = (__hip_bfloat16*)take((size_t)N*32*2);

  float* Apred = (float*)d_out;
  float* z     = Apred + (size_t)N*N;

  (void)hipMemsetAsync(deg, 0, (size_t)N*4, stream);
  k_count  <<<(Etot+255)/256, 256, 0, stream>>>(ei, E, N, deg);
  k_scan   <<<1, 1024, 0, stream>>>(deg, off, cur, N);
  k_scatter<<<(Etot+255)/256, 256, 0, stream>>>(ei, E, N, cur, ssrc, sdst);

  k_linear1<<<N/16, 128, 0, stream>>>(x, W1l, b1l, W1r, b1r, xl1, xr1);
  k_conv1  <<<N, 128, 0, stream>>>(off, ssrc, xl1, xr1, att1, bias1, h1);

  k_linear2<<<N, 64, 0, stream>>>(h1, W2l, b2l, W2r, b2r, xl2, xr2);
  k_conv2  <<<N/4, 256, 0, stream>>>(off, ssrc, xl2, xr2, att2, bias2, z, zb);

  dim3 grid(N/64, N/64);
  k_adj    <<<grid, 256, 0, stream>>>(zb, Apred, N);
}

// Round 7
// 182.708 us; speedup vs baseline: 1.7363x; 1.0943x over previous
//
#include <hip/hip_runtime.h>
#include <hip/hip_bf16.h>
#include <cstdint>
#include <cstddef>

typedef float f32x4 __attribute__((ext_vector_type(4)));
typedef short short8 __attribute__((ext_vector_type(8)));

__device__ __forceinline__ float lrelu(float v){ return v > 0.f ? v : 0.2f*v; }

// ---------------- CSR build (bucket edges by dst) ----------------
__global__ void k_count(const int* __restrict__ ei, int E, int N, int* __restrict__ deg){
  int i = blockIdx.x*blockDim.x + threadIdx.x;
  int tot = E + N;
  if (i >= tot) return;
  int d = (i < E) ? ei[E + i] : (i - E);
  atomicAdd(&deg[d], 1);
}

// single-block exclusive scan over deg[0..n) -> off[0..n], cur = copy of off
__global__ void k_scan(const int* __restrict__ deg, int* __restrict__ off,
                       int* __restrict__ cur, int n){
  __shared__ int wsum[16];
  __shared__ int wpre[17];
  int tid = threadIdx.x;                 // 1024 threads
  int per = (n + 1023) >> 10;
  int base = tid * per;
  int s = 0;
  for (int i = 0; i < per; i++){ int idx = base + i; if (idx < n) s += deg[idx]; }
  int lane = tid & 63, wv = tid >> 6;
  int v = s;
  for (int d = 1; d < 64; d <<= 1){ int o = __shfl_up(v, d, 64); if (lane >= d) v += o; }
  if (lane == 63) wsum[wv] = v;
  __syncthreads();
  if (tid == 0){ int a = 0; for (int w = 0; w < 16; w++){ wpre[w] = a; a += wsum[w]; } wpre[16] = a; }
  __syncthreads();
  int run = wpre[wv] + (v - s);          // exclusive prefix for this thread
  for (int i = 0; i < per; i++){
    int idx = base + i;
    if (idx < n){ off[idx] = run; cur[idx] = run; run += deg[idx]; }
  }
  if (tid == 0) off[n] = wpre[16];
}

__global__ void k_scatter(const int* __restrict__ ei, int E, int N,
                          int* __restrict__ cur, int* __restrict__ ssrc){
  int i = blockIdx.x*blockDim.x + threadIdx.x;
  int tot = E + N;
  if (i >= tot) return;
  int s = (i < E) ? ei[i]     : (i - E);
  int d = (i < E) ? ei[E + i] : (i - E);
  int pos = atomicAdd(&cur[d], 1);
  ssrc[pos] = s;
}

// ------- conv1 linear: xl1/xr1 = x @ W + b  [N,128]; W cols in regs -------
__global__ __launch_bounds__(128) void k_linear1(const float* __restrict__ x,
                          const float* __restrict__ W1l, const float* __restrict__ b1l,
                          const float* __restrict__ W1r, const float* __restrict__ b1r,
                          float* __restrict__ xl1, float* __restrict__ xr1){
  __shared__ float xs[16][32];
  int t = threadIdx.x;
  int r0 = blockIdx.x * 16;
  float wl[32], wr[32];
  #pragma unroll
  for (int k = 0; k < 32; k++){ wl[k] = W1l[k*128 + t]; wr[k] = W1r[k*128 + t]; }
  float bl = b1l[t], br = b1r[t];
  #pragma unroll
  for (int i = 0; i < 4; i++){
    int idx = t + i*128;                 // 0..511
    xs[idx >> 5][idx & 31] = x[r0*32 + idx];
  }
  __syncthreads();
  #pragma unroll 4
  for (int r = 0; r < 16; r++){
    float al = bl, ar = br;
    const float4* xv4 = (const float4*)xs[r];
    #pragma unroll
    for (int q = 0; q < 8; q++){
      float4 xv = xv4[q];
      al += xv.x*wl[q*4+0] + xv.y*wl[q*4+1] + xv.z*wl[q*4+2] + xv.w*wl[q*4+3];
      ar += xv.x*wr[q*4+0] + xv.y*wr[q*4+1] + xv.z*wr[q*4+2] + xv.w*wr[q*4+3];
    }
    xl1[(r0+r)*128 + t] = al;
    xr1[(r0+r)*128 + t] = ar;
  }
}

// -- conv1 fused online-softmax aggregate: one block (128 thr) per dst -----
// Single pass over incoming edges: per-edge logit via 16-lane dot reduce,
// then flash-style (m, s, acc) rescale update. One gather of xl1[src] total.
__global__ __launch_bounds__(128) void k_conv1(const int* __restrict__ off,
                       const int* __restrict__ ssrc,
                       const float* __restrict__ xl1, const float* __restrict__ xr1,
                       const float* __restrict__ att1, const float* __restrict__ bias1,
                       float* __restrict__ h1){
  int d = blockIdx.x;
  int f = threadIdx.x;                   // feature 0..127 (h = f>>4)
  int j0 = off[d], j1 = off[d+1];
  float xr_f = xr1[d*128 + f];
  float at_f = att1[f];                  // att1 [8][16] row-major matches f
  float m = -1e30f, s = 0.f, acc = 0.f;
  #pragma unroll 2
  for (int j = j0; j < j1; j++){
    int src = ssrc[j];
    float xlv = xl1[src*128 + f];
    float tv = lrelu(xlv + xr_f) * at_f;
    #pragma unroll
    for (int k = 1; k < 16; k <<= 1) tv += __shfl_xor(tv, k, 64);
    float nm = fmaxf(m, tv);
    float sc = __expf(m - nm);
    float p  = __expf(tv - nm);
    s   = s*sc + p;
    acc = acc*sc + p*xlv;
    m = nm;
  }
  h1[d*128 + f] = acc/(s + 1e-16f) + bias1[f];
}

// ---------------- conv2 linear: xl2/xr2 = h1 @ W2 + b2  [N,32] -------------
__global__ __launch_bounds__(64) void k_linear2(const float* __restrict__ h1,
                          const float* __restrict__ W2l, const float* __restrict__ b2l,
                          const float* __restrict__ W2r, const float* __restrict__ b2r,
                          float* __restrict__ xl2, float* __restrict__ xr2){
  __shared__ float hs[128];
  int n = blockIdx.x, t = threadIdx.x;   // 64 threads
  hs[t]      = h1[n*128 + t];
  hs[t + 64] = h1[n*128 + t + 64];
  __syncthreads();
  int c = t & 31;
  bool left = t < 32;
  const float* W = left ? W2l : W2r;
  float a = left ? b2l[c] : b2r[c];
  #pragma unroll 8
  for (int k = 0; k < 128; k++) a += hs[k] * W[k*32 + c];
  if (left) xl2[n*32 + c] = a; else xr2[n*32 + c] = a;
}

// -- conv2 fused online-softmax+agg+L2norm: wave per dst, 4 dst per block --
// Each 32-lane half processes alternate edges with its own (m,s,acc);
// states merged at the end with the standard online-softmax combine.
__global__ __launch_bounds__(256) void k_conv2(const int* __restrict__ off,
                       const int* __restrict__ ssrc,
                       const float* __restrict__ xl2, const float* __restrict__ xr2,
                       const float* __restrict__ att2, const float* __restrict__ bias2,
                       float* __restrict__ z, __hip_bfloat16* __restrict__ zb){
  int t = threadIdx.x;
  int w = t >> 6, lane = t & 63;
  int half = lane >> 5, c = lane & 31;
  int d = blockIdx.x*4 + w;
  int j0 = off[d], j1 = off[d+1];
  float xr_c = xr2[d*32 + c];
  float at_c = att2[c];
  float m = -1e30f, s = 0.f, acc = 0.f;
  #pragma unroll 2
  for (int j = j0 + half; j < j1; j += 2){
    int src = ssrc[j];
    float xlv = xl2[src*32 + c];
    float tv = lrelu(xlv + xr_c) * at_c;
    #pragma unroll
    for (int k = 1; k < 32; k <<= 1) tv += __shfl_xor(tv, k, 64);  // within half
    float nm = fmaxf(m, tv);
    float sc = __expf(m - nm);
    float p  = __expf(tv - nm);
    s   = s*sc + p;
    acc = acc*sc + p*xlv;
    m = nm;
  }
  // merge the two halves' online states
  float mo = __shfl_xor(m, 32, 64);
  float so = __shfl_xor(s, 32, 64);
  float ao = __shfl_xor(acc, 32, 64);
  float nm = fmaxf(m, mo);
  float sc0 = __expf(m - nm), sc1 = __expf(mo - nm);
  s   = s*sc0 + so*sc1;
  acc = acc*sc0 + ao*sc1;
  float v = acc/(s + 1e-16f) + bias2[c];
  float ss = v*v;
  #pragma unroll
  for (int k = 1; k < 32; k <<= 1) ss += __shfl_xor(ss, k, 64);
  if (half == 0){
    float zv = v / fmaxf(sqrtf(ss), 1e-12f);
    z[d*32 + c] = zv;
    zb[d*32 + c] = __float2bfloat16(zv);
  }
}

// ---------------- A_pred = sigmoid(z z^T) via bf16 MFMA --------------------
// LDS-bounced epilogue: float4 stores, 16 consecutive lanes = 256 B/instr.
__global__ __launch_bounds__(256) void k_adj(const __hip_bfloat16* __restrict__ zb,
                                             float* __restrict__ out, int N){
  __shared__ float tile[64][68];
  int tid = threadIdx.x;
  int w = tid >> 6, l = tid & 63;
  int hi = l >> 4, lo = l & 15;
  int r0 = blockIdx.y*64, c0 = blockIdx.x*64;
  short8 a = *(const short8*)(zb + (size_t)(r0 + w*16 + lo)*32 + hi*8);
  f32x4 acc[4];
  #pragma unroll
  for (int ct = 0; ct < 4; ct++){
    short8 b = *(const short8*)(zb + (size_t)(c0 + ct*16 + lo)*32 + hi*8);
    acc[ct] = __builtin_amdgcn_mfma_f32_16x16x32_bf16(a, b, (f32x4){0.f,0.f,0.f,0.f}, 0, 0, 0);
  }
  #pragma unroll
  for (int ct = 0; ct < 4; ct++){
    #pragma unroll
    for (int r = 0; r < 4; r++)
      tile[w*16 + hi*4 + r][ct*16 + lo] = 1.f/(1.f + __expf(-acc[ct][r]));
  }
  __syncthreads();
  #pragma unroll
  for (int k = 0; k < 4; k++){
    int g = tid + k*256;                 // 0..1023 float4 slots
    int row = g >> 4, c4 = (g & 15)*4;
    f32x4 v = *(const f32x4*)&tile[row][c4];
    __builtin_nontemporal_store(v, (f32x4*)&out[(size_t)(r0 + row)*N + c0 + c4]);
  }
}

extern "C" void kernel_launch(void* const* d_in, const int* in_sizes, int n_in,
                              void* d_out, int out_size, void* d_ws, size_t ws_size,
                              hipStream_t stream){
  const float* x     = (const float*)d_in[0];
  const int*   ei    = (const int*)  d_in[1];
  const float* W1l   = (const float*)d_in[2];
  const float* b1l   = (const float*)d_in[3];
  const float* W1r   = (const float*)d_in[4];
  const float* b1r   = (const float*)d_in[5];
  const float* att1  = (const float*)d_in[6];
  const float* bias1 = (const float*)d_in[7];
  const float* W2l   = (const float*)d_in[8];
  const float* b2l   = (const float*)d_in[9];
  const float* W2r   = (const float*)d_in[10];
  const float* b2r   = (const float*)d_in[11];
  const float* att2  = (const float*)d_in[12];
  const float* bias2 = (const float*)d_in[13];

  const int N = in_sizes[0] / 32;
  const int E = in_sizes[1] / 2;
  const int Etot = E + N;

  char* w = (char*)d_ws;
  size_t p = 0;
  auto take = [&](size_t bytes)->char*{
    char* r = w + p;
    p = (p + bytes + 255) & ~(size_t)255;
    return r;
  };
  int*   deg  = (int*)  take((size_t)N*4);
  int*   off  = (int*)  take((size_t)(N+1)*4);
  int*   cur  = (int*)  take((size_t)N*4);
  int*   ssrc = (int*)  take((size_t)Etot*4);
  float* xl1  = (float*)take((size_t)N*128*4);
  float* xr1  = (float*)take((size_t)N*128*4);
  float* h1   = (float*)take((size_t)N*128*4);
  float* xl2  = (float*)take((size_t)N*32*4);
  float* xr2  = (float*)take((size_t)N*32*4);
  __hip_bfloat16* zb = (__hip_bfloat16*)take((size_t)N*32*2);

  float* Apred = (float*)d_out;
  float* z     = Apred + (size_t)N*N;

  (void)hipMemsetAsync(deg, 0, (size_t)N*4, stream);
  k_count  <<<(Etot+255)/256, 256, 0, stream>>>(ei, E, N, deg);
  k_scan   <<<1, 1024, 0, stream>>>(deg, off, cur, N);
  k_scatter<<<(Etot+255)/256, 256, 0, stream>>>(ei, E, N, cur, ssrc);

  k_linear1<<<N/16, 128, 0, stream>>>(x, W1l, b1l, W1r, b1r, xl1, xr1);
  k_conv1  <<<N, 128, 0, stream>>>(off, ssrc, xl1, xr1, att1, bias1, h1);

  k_linear2<<<N, 64, 0, stream>>>(h1, W2l, b2l, W2r, b2r, xl2, xr2);
  k_conv2  <<<N/4, 256, 0, stream>>>(off, ssrc, xl2, xr2, att2, bias2, z, zb);

  dim3 grid(N/64, N/64);
  k_adj    <<<grid, 256, 0, stream>>>(zb, Apred, N);
}